// Round 12
// baseline (332.707 us; speedup 1.0000x reference)
//
#include <hip/hip_runtime.h>
#include <stdint.h>

// Problem constants (fixed by setup_inputs; all tensors f32)
#define B_ROWS 4096
#define D_IN   784
#define H_DIM  800
#define D_OUT  10
#define T_SIM  32
#define N_ELEM (B_ROWS * D_IN)   // 3211264
#define NKT    49                // 784 / 16
#define CAP    512               // spiking-list cap/row (mean ~376, sd ~14)

// ---------------------------------------------------------------------------
// Bit-exact JAX threefry2x32 (key = PRNGKey(42) = {0, 42})
// ---------------------------------------------------------------------------
__device__ __forceinline__ void threefry2x32(uint32_t k0, uint32_t k1,
                                             uint32_t& x0, uint32_t& x1) {
  uint32_t ks0 = k0, ks1 = k1, ks2 = k0 ^ k1 ^ 0x1BD11BDAu;
  x0 += ks0; x1 += ks1;
#define TF_RND(r) { x0 += x1; x1 = (x1 << (r)) | (x1 >> (32 - (r))); x1 ^= x0; }
  TF_RND(13) TF_RND(15) TF_RND(26) TF_RND(6)
  x0 += ks1; x1 += ks2 + 1u;
  TF_RND(17) TF_RND(29) TF_RND(16) TF_RND(24)
  x0 += ks2; x1 += ks0 + 2u;
  TF_RND(13) TF_RND(15) TF_RND(26) TF_RND(6)
  x0 += ks0; x1 += ks1 + 3u;
  TF_RND(17) TF_RND(29) TF_RND(16) TF_RND(24)
  x0 += ks1; x1 += ks2 + 4u;
  TF_RND(13) TF_RND(15) TF_RND(26) TF_RND(6)
  x0 += ks2; x1 += ks0 + 5u;
#undef TF_RND
}

// K0: bit-packed x_fixed. Thread = (row, kt): 16 elements -> one u16.
// Same per-element comparison as every passing round (exact bits). Layout:
// xb[panel=row>>7][kt][ml=row&127] -> GEMM stages the panel with a straight
// contiguous copy. Bit j of word (row,kt) = element k = kt*16+j (ascending).
__global__ __launch_bounds__(256) void gen_xbits(const float* __restrict__ x,
                                                 uint16_t* __restrict__ xb) {
  int tid = blockIdx.x * 256 + threadIdx.x;    // 784 * 256 = 200704 = 4096*49
  int row = tid / NKT;
  int kt  = tid - row * NKT;
  const float* xp = x + row * D_IN + kt * 16;  // 64B-aligned
  float xv[16];
#pragma unroll
  for (int q = 0; q < 4; ++q) {
    float4 v = *(const float4*)(xp + 4 * q);
    xv[4 * q + 0] = v.x; xv[4 * q + 1] = v.y;
    xv[4 * q + 2] = v.z; xv[4 * q + 3] = v.w;
  }
  uint32_t base = (uint32_t)(row * D_IN + kt * 16);
  uint32_t bits = 0;
#pragma unroll
  for (int j = 0; j < 16; ++j) {
    uint32_t c0 = 0u, c1 = base + j;           // partitionable: counter (0, i)
    threefry2x32(0u, 42u, c0, c1);
    uint32_t b = c0 ^ c1;
    float u = __uint_as_float((b >> 9) | 0x3F800000u) - 1.0f;
    bits |= (u < xv[j]) ? (1u << j) : 0u;
  }
  xb[(row >> 7) * (NKT * 128) + kt * 128 + (row & 127)] = (uint16_t)bits;
}

// ---------------------------------------------------------------------------
// K1: R9 skeleton (tile 128x64, 2-barrier kt loop, reg prefetch, epilogue —
// measured 165 us) with A as a 12.5 KB bit panel: 1 ds_read_b128 per kt for
// the A fragment (was 32). a = bfe(bit) -> cvt gives exact 0.0f/1.0f, so
// fma(a,b,acc) is the identical round(acc+b)/identity ascending-k chain.
// ---------------------------------------------------------------------------
#define BM 128
#define BN 64
#define BK 16

__global__ __launch_bounds__(256) void gemm_periods(const uint16_t* __restrict__ xb,
                                                    const float* __restrict__ W1,
                                                    const float* __restrict__ b1,
                                                    uint8_t* __restrict__ pb) {
  __shared__ __align__(16) uint16_t Abits[NKT * BM];   // [kt][ml], 12544 B
  __shared__ __align__(16) float Bs[BK][BN + 4];
  const int m0 = blockIdx.y * BM;
  const int n0 = blockIdx.x * BN;
  const int t  = threadIdx.x;        // 0..255
  const int tx = t & 15, ty = t >> 4;
  const int br = t >> 2;             // 0..63  B staging row
  const int bk = (t & 3) * 4;        // 0,4,8,12
  const int hB = n0 + br;
  const bool bOK = (hB < H_DIM);
  const float* bptr = W1 + (bOK ? hB : 0) * D_IN + bk;

  // Stage the A-bit panel once (contiguous, 784 uint4)
  {
    const uint4* src = (const uint4*)(xb + (size_t)blockIdx.y * (NKT * BM));
    for (int i = t; i < 784; i += 256) ((uint4*)Abits)[i] = src[i];
  }
  float4 b0 = *(const float4*)(bptr);
  if (!bOK) { b0.x = b0.y = b0.z = b0.w = 0.0f; }

  float acc[8][4] = {};
  for (int kt = 0; kt < D_IN; kt += BK) {   // ascending k, single acc
    Bs[bk + 0][br] = b0.x; Bs[bk + 1][br] = b0.y;
    Bs[bk + 2][br] = b0.z; Bs[bk + 3][br] = b0.w;
    __syncthreads();                        // also covers Abits staging (kt=0)
    if (kt + BK < D_IN) {                   // prefetch next B tile
      b0 = *(const float4*)(bptr + kt + BK);
      if (!bOK) { b0.x = b0.y = b0.z = b0.w = 0.0f; }
    }
    // A fragment: 8 rows x 16 bits = 16 B, one b128
    uint4 av = *(const uint4*)&Abits[(kt >> 4) * BM + ty * 8];
#pragma unroll
    for (int kk = 0; kk < BK; kk++) {
      float4 bv = *(const float4*)&Bs[kk][tx * 4];
      float a[8];
      a[0] = (float)((av.x >> kk) & 1u);
      a[1] = (float)((av.x >> (kk + 16)) & 1u);
      a[2] = (float)((av.y >> kk) & 1u);
      a[3] = (float)((av.y >> (kk + 16)) & 1u);
      a[4] = (float)((av.z >> kk) & 1u);
      a[5] = (float)((av.z >> (kk + 16)) & 1u);
      a[6] = (float)((av.w >> kk) & 1u);
      a[7] = (float)((av.w >> (kk + 16)) & 1u);
      float b[4] = {bv.x, bv.y, bv.z, bv.w};
#pragma unroll
      for (int mi = 0; mi < 8; mi++)
#pragma unroll
        for (int ni = 0; ni < 4; ni++)
          acc[mi][ni] = __builtin_fmaf(a[mi], b[ni], acc[mi][ni]);
    }
    __syncthreads();
  }
  // Epilogue (R9 verbatim): + b1, then exact f32 IF-period loop
  const int hOut = n0 + tx * 4;
  if (hOut < H_DIM) {
    float4 bb = *(const float4*)&b1[hOut];
#pragma unroll
    for (int mi = 0; mi < 8; mi++) {
      int m = m0 + ty * 8 + mi;
      float c4[4] = {acc[mi][0] + bb.x, acc[mi][1] + bb.y,
                     acc[mi][2] + bb.z, acc[mi][3] + bb.w};
      uint32_t packed = 0;
#pragma unroll
      for (int ni = 0; ni < 4; ni++) {
        float c = c4[ni];
        float v = 0.0f;
        int p = 0;
#pragma unroll 1
        for (int s = 1; s <= T_SIM; s++) {
          float h1 = v + c;                   // f32 add, as reference
          if (h1 >= 1.0f) { p = s; break; }
          v = h1;
        }
        packed |= (uint32_t)p << (8 * ni);
      }
      *(uint32_t*)&pb[(size_t)m * H_DIM + hOut] = packed;
    }
  }
}

// ---------------------------------------------------------------------------
// K2: SNN scan, R9's 320-thread shape; exec reads 4 entries per 3 b128
// (mask uint4 + two float4 of interleaved w-pairs), all <=2-distinct
// addresses (conflict-free). Exactness: per (row,t,o) the same ascending-h
// single-accumulator gated fold as every passing round — skip of
// never-spiking h is the +0 identity; each step is +w or +0 (select form;
// pads have mask=0 and w=0).
// ---------------------------------------------------------------------------
__global__ __launch_bounds__(320) void snn_scan(const uint8_t* __restrict__ pb,
                                                const float* __restrict__ W2,
                                                const float* __restrict__ b2,
                                                float* __restrict__ out) {
  __shared__ __align__(16) uint32_t mkS[2][CAP];        // 4 KB, 0-padded
  __shared__ uint16_t hidxS[2][CAP];                    // 2 KB
  __shared__ __align__(16) float wst2[2 * 5 * CAP * 2]; // 40 KB, w-pairs
  __shared__ int      lenS[2];
  __shared__ uint32_t mtbl[T_SIM + 1];
  __shared__ float    c2s[2][T_SIM][D_OUT];
  __shared__ float    b2f[D_OUT];
  const int tid  = threadIdx.x;               // 0..319
  const int row0 = blockIdx.x * 2;

  if (tid <= T_SIM) {                         // mask of multiples of p
    uint32_t mk = 0;
    if (tid) for (int s = tid; s <= T_SIM; s += tid) mk |= 1u << (s - 1);
    mtbl[tid] = mk;
  }
  if (tid < D_OUT) b2f[tid] = b2[tid];
  __syncthreads();

  // ---- Build: waves 0-1 ballot-compact the period bytes (ascending h) ----
  if (tid < 128) {
    const int r = tid >> 6, ln = tid & 63;
    const uint64_t lm = (1ull << ln) - 1ull;
    const uint8_t* prow = pb + (size_t)(row0 + r) * H_DIM;
    uint8_t pv[13];
#pragma unroll
    for (int ch = 0; ch < 13; ++ch) {
      int h = ch * 64 + ln;
      pv[ch] = (h < H_DIM) ? prow[h] : (uint8_t)0;
    }
    int off = 0;
#pragma unroll
    for (int ch = 0; ch < 13; ++ch) {
      bool g = (pv[ch] != 0);
      uint64_t bal = __ballot(g);
      int pos = off + __popcll(bal & lm);
      if (g && pos < CAP) {
        hidxS[r][pos] = (uint16_t)(ch * 64 + ln);
        mkS[r][pos]   = mtbl[pv[ch]];
      }
      off += __popcll(bal);
    }
    if (ln == 0) lenS[r] = off;
  }
  __syncthreads();

  const int L0 = min(lenS[0], CAP), L1 = min(lenS[1], CAP);
  const bool ovf = (lenS[0] > CAP) || (lenS[1] > CAP);
  const int Lpad = (max(L0, L1) + 63) & ~63;  // multiple of 64, <= CAP

  // ---- Pad mask stream ----
  for (int e = tid; e < 2 * CAP; e += 320) {
    int r = e >= CAP ? 1 : 0, i = e - r * CAP;
    if (i >= (r ? L1 : L0)) mkS[r][i] = 0u;
  }
  __syncthreads();                            // hidx/len visible to all

  // ---- Gather w-pair streams (all threads, W2 is 32 KB L1/L2-hot) ----
#pragma unroll
  for (int r = 0; r < 2; ++r) {
    const int Lr = r ? L1 : L0;
#pragma unroll
    for (int j = 0; j < 5; ++j) {
      float* dst = &wst2[(r * 5 + j) * (2 * CAP)];
      for (int i = tid; i < Lpad; i += 320) {
        float2 w = {0.0f, 0.0f};
        if (i < Lr) {
          int h = hidxS[r][i];
          w.x = W2[(2 * j) * H_DIM + h];
          w.y = W2[(2 * j + 1) * H_DIM + h];
        }
        *(float2*)&dst[2 * i] = w;
      }
    }
  }
  __syncthreads();

  // ---- Exec: wave j, lanes (t, r); 3 b128 per 4 entries ----
  {
    const int j = tid >> 6;                   // 0..4
    const int lane = tid & 63;
    const int t = lane & 31;
    const int r = lane >> 5;
    float s0 = 0.0f, s1 = 0.0f;
    if (!ovf) {
      const uint32_t* mp = mkS[r];
      const float* wp = &wst2[(r * 5 + j) * (2 * CAP)];
#pragma unroll 2
      for (int i4 = 0; i4 < Lpad; i4 += 4) {
        uint4  M  = *(const uint4*)&mp[i4];           // broadcast/2-distinct
        float4 wA = *(const float4*)&wp[2 * i4];      // entries i4, i4+1
        float4 wB = *(const float4*)&wp[2 * i4 + 4];  // entries i4+2, i4+3
        bool g0 = (M.x >> t) & 1u;
        s0 += g0 ? wA.x : 0.0f;  s1 += g0 ? wA.y : 0.0f;
        bool g1 = (M.y >> t) & 1u;
        s0 += g1 ? wA.z : 0.0f;  s1 += g1 ? wA.w : 0.0f;
        bool g2 = (M.z >> t) & 1u;
        s0 += g2 ? wB.x : 0.0f;  s1 += g2 ? wB.y : 0.0f;
        bool g3 = (M.w >> t) & 1u;
        s0 += g3 ? wB.z : 0.0f;  s1 += g3 ? wB.w : 0.0f;
      }
    } else {                                  // overflow fallback: gated scan
      const uint8_t* prow = pb + (size_t)(row0 + r) * H_DIM;
      const uint32_t vbit = 1u << t;
      for (int h = 0; h < H_DIM; ++h) {
        uint32_t mk = mtbl[prow[h]];
        float w0 = W2[(2 * j) * H_DIM + h];
        float w1 = W2[(2 * j + 1) * H_DIM + h];
        s0 += (mk & vbit) ? w0 : 0.0f;
        s1 += (mk & vbit) ? w1 : 0.0f;
      }
    }
    c2s[r][t][2 * j]     = s0;
    c2s[r][t][2 * j + 1] = s1;
  }
  __syncthreads();

  // ---- Layer-2 IF scan + spike count (exact f32 ref order) ----
  if (tid < 2 * D_OUT) {
    const int r = tid / D_OUT, o = tid % D_OUT;
    const float bb = b2f[o];
    float v = 0.0f; int cnt = 0;
#pragma unroll
    for (int t = 0; t < T_SIM; ++t) {
      float cur2 = c2s[r][t][o] + bb;         // f32 add of b2, like ref
      float h2 = v + cur2;                    // f32 add
      bool spk = (h2 >= 1.0f);
      cnt += spk ? 1 : 0;
      v = spk ? 0.0f : h2;
    }
    out[(size_t)(row0 + r) * D_OUT + o] = (float)cnt;
  }
}

// ---------------------------------------------------------------------------
extern "C" void kernel_launch(void* const* d_in, const int* in_sizes, int n_in,
                              void* d_out, int out_size, void* d_ws, size_t ws_size,
                              hipStream_t stream) {
  const float* x  = (const float*)d_in[0];
  const float* W1 = (const float*)d_in[1];
  const float* b1 = (const float*)d_in[2];
  const float* W2 = (const float*)d_in[3];
  const float* b2 = (const float*)d_in[4];
  float* outp = (float*)d_out;

  uint16_t* xb = (uint16_t*)d_ws;                   // 200704 u16 (401 KB)
  uint8_t*  pbuf = (uint8_t*)d_ws + 401408;         // B*H bytes (3.28 MB)

  gen_xbits<<<784, 256, 0, stream>>>(x, xb);

  dim3 g1((H_DIM + BN - 1) / BN, B_ROWS / BM);      // 13 x 32 = 416 blocks
  gemm_periods<<<g1, 256, 0, stream>>>(xb, W1, b1, pbuf);

  snn_scan<<<B_ROWS / 2, 320, 0, stream>>>(pbuf, W2, b2, outp);
}

// Round 13
// 286.353 us; speedup vs baseline: 1.1619x; 1.1619x over previous
//
#include <hip/hip_runtime.h>
#include <stdint.h>

// Problem constants (fixed by setup_inputs; all tensors f32)
#define B_ROWS 4096
#define D_IN   784
#define H_DIM  800
#define D_OUT  10
#define T_SIM  32
#define N_ELEM (B_ROWS * D_IN)   // 3211264
#define CAP    512               // spiking-list cap/row (mean ~376, sd ~14)

// ---------------------------------------------------------------------------
// Bit-exact JAX threefry2x32 (key = PRNGKey(42) = {0, 42})
// ---------------------------------------------------------------------------
__device__ __forceinline__ void threefry2x32(uint32_t k0, uint32_t k1,
                                             uint32_t& x0, uint32_t& x1) {
  uint32_t ks0 = k0, ks1 = k1, ks2 = k0 ^ k1 ^ 0x1BD11BDAu;
  x0 += ks0; x1 += ks1;
#define TF_RND(r) { x0 += x1; x1 = (x1 << (r)) | (x1 >> (32 - (r))); x1 ^= x0; }
  TF_RND(13) TF_RND(15) TF_RND(26) TF_RND(6)
  x0 += ks1; x1 += ks2 + 1u;
  TF_RND(17) TF_RND(29) TF_RND(16) TF_RND(24)
  x0 += ks2; x1 += ks0 + 2u;
  TF_RND(13) TF_RND(15) TF_RND(26) TF_RND(6)
  x0 += ks0; x1 += ks1 + 3u;
  TF_RND(17) TF_RND(29) TF_RND(16) TF_RND(24)
  x0 += ks1; x1 += ks2 + 4u;
  TF_RND(13) TF_RND(15) TF_RND(26) TF_RND(6)
  x0 += ks2; x1 += ks0 + 5u;
#undef TF_RND
}

// K0 (R9 verbatim): x_fixed[i] = (u[i] < x[i]) ? 1 : 0.
__global__ __launch_bounds__(256) void gen_xfixed(const float* __restrict__ x,
                                                  float* __restrict__ xf) {
  int i = blockIdx.x * blockDim.x + threadIdx.x;
  if (i >= N_ELEM) return;
  uint32_t c0 = 0u, c1 = (uint32_t)i;
  threefry2x32(0u, 42u, c0, c1);
  uint32_t bits = c0 ^ c1;
  float u = __uint_as_float((bits >> 9) | 0x3F800000u) - 1.0f;
  xf[i] = (u < x[i]) ? 1.0f : 0.0f;
}

// ---------------------------------------------------------------------------
// K1: fused GEMM + period epilogue, float-A 64x64 tile.
// Bit-exact f32 ascending-k single-accumulator fma chain (unchanged math,
// passing since R5). 832 blocks -> 3.25 waves/SIMD (2x R9's latency hiding);
// aligned LDS rows (stride 68) give true ds_read_b128: 2 b128 + 16 fma / kk.
// ---------------------------------------------------------------------------
#define BM 64
#define BN 64
#define BK 16

__global__ __launch_bounds__(256) void gemm_periods(const float* __restrict__ xf,
                                                    const float* __restrict__ W1,
                                                    const float* __restrict__ b1,
                                                    uint8_t* __restrict__ pb) {
  __shared__ __align__(16) float As[BK][BM + 4];   // stride 272B (16B mult)
  __shared__ __align__(16) float Bs[BK][BN + 4];
  const int m0 = blockIdx.y * BM;
  const int n0 = blockIdx.x * BN;
  const int t  = threadIdx.x;        // 0..255
  const int tx = t & 15, ty = t >> 4;
  const int sM = t >> 2;             // 0..63 staging row
  const int sK = (t & 3) * 4;        // 0,4,8,12
  const int hB = n0 + sM;
  const bool bOK = (hB < H_DIM);
  const float* aptr = xf + (m0 + sM) * D_IN + sK;
  const float* bptr = W1 + (bOK ? hB : 0) * D_IN + sK;

  float4 a4 = *(const float4*)(aptr);
  float4 b4 = *(const float4*)(bptr);
  if (!bOK) { b4.x = b4.y = b4.z = b4.w = 0.0f; }

  float acc[4][4] = {};
  for (int kt = 0; kt < D_IN; kt += BK) {   // 784 = 49*16, ascending k
    As[sK + 0][sM] = a4.x; As[sK + 1][sM] = a4.y;
    As[sK + 2][sM] = a4.z; As[sK + 3][sM] = a4.w;
    Bs[sK + 0][sM] = b4.x; Bs[sK + 1][sM] = b4.y;
    Bs[sK + 2][sM] = b4.z; Bs[sK + 3][sM] = b4.w;
    __syncthreads();
    if (kt + BK < D_IN) {                   // prefetch next tile
      a4 = *(const float4*)(aptr + kt + BK);
      b4 = *(const float4*)(bptr + kt + BK);
      if (!bOK) { b4.x = b4.y = b4.z = b4.w = 0.0f; }
    }
#pragma unroll
    for (int kk = 0; kk < BK; kk++) {       // strict ascending k, single acc
      float4 av = *(const float4*)&As[kk][ty * 4];   // ds_read_b128
      float4 bv = *(const float4*)&Bs[kk][tx * 4];   // ds_read_b128
      float a[4] = {av.x, av.y, av.z, av.w};
      float b[4] = {bv.x, bv.y, bv.z, bv.w};
#pragma unroll
      for (int mi = 0; mi < 4; mi++)
#pragma unroll
        for (int ni = 0; ni < 4; ni++)
          acc[mi][ni] = __builtin_fmaf(a[mi], b[ni], acc[mi][ni]);
    }
    __syncthreads();
  }
  // Epilogue: + b1 (f32 add like ref), then exact f32 IF-period loop
  const int hOut = n0 + tx * 4;              // multiple of 4
  if (hOut < H_DIM) {
    float4 bb = *(const float4*)&b1[hOut];
#pragma unroll
    for (int mi = 0; mi < 4; mi++) {
      int m = m0 + ty * 4 + mi;
      float c4[4] = {acc[mi][0] + bb.x, acc[mi][1] + bb.y,
                     acc[mi][2] + bb.z, acc[mi][3] + bb.w};
      uint32_t packed = 0;
#pragma unroll
      for (int ni = 0; ni < 4; ni++) {
        float c = c4[ni];
        float v = 0.0f;
        int p = 0;
#pragma unroll 1
        for (int s = 1; s <= T_SIM; s++) {
          float h1 = v + c;                   // f32 add, as reference
          if (h1 >= 1.0f) { p = s; break; }
          v = h1;
        }
        packed |= (uint32_t)p << (8 * ni);
      }
      *(uint32_t*)&pb[(size_t)m * H_DIM + hOut] = packed;
    }
  }
}

// ---------------------------------------------------------------------------
// K2: SNN scan — R9 structure (best measured: 126 us) with mask+haddr packed
// into one u64 stream: exec is 2 LDS ops/entry (both <=2-distinct broadcast).
// Exactness: per (row,t,o) the same ascending-h single-accumulator gated
// fold as every passing round — never-spiking h skipped (+0 identity), each
// included step is +w or +0 (select form; pads have mask=0 -> +0).
// ---------------------------------------------------------------------------
__global__ __launch_bounds__(320) void snn_scan(const uint8_t* __restrict__ pb,
                                                const float* __restrict__ W2,
                                                const float* __restrict__ b2,
                                                float* __restrict__ out) {
  __shared__ __align__(16) float W2T[H_DIM * D_OUT];  // [h][o], 32000 B
  __shared__ __align__(8) uint2 pkS[2][CAP];          // {haddr, mask}, 8 KB
  __shared__ int      lenS[2];
  __shared__ uint32_t mtbl[T_SIM + 1];
  __shared__ float    c2s[2][T_SIM][D_OUT];
  __shared__ float    b2f[D_OUT];
  const int tid  = threadIdx.x;               // 0..319
  const int row0 = blockIdx.x * 2;

  if (tid <= T_SIM) {                         // mask of multiples of p
    uint32_t mk = 0;
    if (tid) for (int s = tid; s <= T_SIM; s += tid) mk |= 1u << (s - 1);
    mtbl[tid] = mk;
  }
  if (tid < D_OUT) b2f[tid] = b2[tid];
  __syncthreads();

  // ---- Build (waves 0-1) || W2T staging (waves 2-4) ----
  if (tid < 128) {
    const int r = tid >> 6, ln = tid & 63;
    const uint64_t lm = (1ull << ln) - 1ull;
    const uint8_t* prow = pb + (size_t)(row0 + r) * H_DIM;
    uint8_t pv[13];
#pragma unroll
    for (int ch = 0; ch < 13; ++ch) {         // independent coalesced loads
      int h = ch * 64 + ln;
      pv[ch] = (h < H_DIM) ? prow[h] : (uint8_t)0;
    }
    int off = 0;
#pragma unroll
    for (int ch = 0; ch < 13; ++ch) {
      bool g = (pv[ch] != 0);
      uint64_t bal = __ballot(g);
      int pos = off + __popcll(bal & lm);
      if (g && pos < CAP) {
        uint2 pk;
        pk.x = (uint32_t)((ch * 64 + ln) * 40);  // byte offset into W2T row
        pk.y = mtbl[pv[ch]];
        pkS[r][pos] = pk;
      }
      off += __popcll(bal);
    }
    if (ln == 0) lenS[r] = off;
  } else {
    for (int e = tid - 128; e < H_DIM * D_OUT; e += 192) {
      int o = e / H_DIM, h = e - o * H_DIM;
      W2T[h * D_OUT + o] = W2[e];              // coalesced global read
    }
  }
  __syncthreads();

  const int L0 = min(lenS[0], CAP), L1 = min(lenS[1], CAP);
  const bool ovf = (lenS[0] > CAP) || (lenS[1] > CAP);
  const int Lpad = (max(L0, L1) + 63) & ~63;   // multiple of 64, <= CAP

  // ---- Zero-pad streams to uniform length ----
  for (int e = tid; e < 2 * CAP; e += 320) {
    int r = e >= CAP ? 1 : 0, i = e - r * CAP;
    if (i >= (r ? L1 : L0) && i < Lpad) { pkS[r][i].x = 0u; pkS[r][i].y = 0u; }
  }
  __syncthreads();

  // ---- Exec: wave j = o-pair, lanes (t, r); 2 LDS ops per entry ----
  {
    const int j = tid >> 6;                    // 0..4
    const int lane = tid & 63;
    const int t = lane & 31;
    const int r = lane >> 5;
    float s0 = 0.0f, s1 = 0.0f;
    if (!ovf) {
      const uint2* pp = pkS[r];
      const char* wbase = (const char*)W2T + 8 * j;
#pragma unroll 4
      for (int i = 0; i < Lpad; ++i) {
        uint2 pk = pp[i];                      // b64, 2-distinct broadcast
        float2 w = *(const float2*)(wbase + pk.x);  // b64, 2-distinct
        bool g = (pk.y >> t) & 1u;
        s0 += g ? w.x : 0.0f;                  // identical op to ref (+w / +0)
        s1 += g ? w.y : 0.0f;
      }
    } else {                                   // overflow fallback: gated scan
      const uint8_t* prow = pb + (size_t)(row0 + r) * H_DIM;
      const uint32_t vbit = 1u << t;
      for (int h = 0; h < H_DIM; ++h) {
        uint32_t mk = mtbl[prow[h]];
        float2 w = *(const float2*)&W2T[h * D_OUT + 2 * j];
        s0 += (mk & vbit) ? w.x : 0.0f;
        s1 += (mk & vbit) ? w.y : 0.0f;
      }
    }
    c2s[r][t][2 * j]     = s0;
    c2s[r][t][2 * j + 1] = s1;
  }
  __syncthreads();

  // ---- Layer-2 IF scan + spike count (exact f32 ref order) ----
  if (tid < 2 * D_OUT) {
    const int r = tid / D_OUT, o = tid % D_OUT;
    const float bb = b2f[o];
    float v = 0.0f; int cnt = 0;
#pragma unroll
    for (int t = 0; t < T_SIM; ++t) {
      float cur2 = c2s[r][t][o] + bb;          // f32 add of b2, like ref
      float h2 = v + cur2;                     // f32 add
      bool spk = (h2 >= 1.0f);
      cnt += spk ? 1 : 0;
      v = spk ? 0.0f : h2;
    }
    out[(size_t)(row0 + r) * D_OUT + o] = (float)cnt;
  }
}

// ---------------------------------------------------------------------------
extern "C" void kernel_launch(void* const* d_in, const int* in_sizes, int n_in,
                              void* d_out, int out_size, void* d_ws, size_t ws_size,
                              hipStream_t stream) {
  const float* x  = (const float*)d_in[0];
  const float* W1 = (const float*)d_in[1];
  const float* b1 = (const float*)d_in[2];
  const float* W2 = (const float*)d_in[3];
  const float* b2 = (const float*)d_in[4];
  float* outp = (float*)d_out;

  float*   xf = (float*)d_ws;                       // N_ELEM f32 (12.85 MB)
  uint8_t* pbuf = (uint8_t*)(xf + N_ELEM);          // B*H bytes  (3.28 MB)

  gen_xfixed<<<N_ELEM / 256, 256, 0, stream>>>(x, xf);

  dim3 g1((H_DIM + BN - 1) / BN, B_ROWS / BM);      // 13 x 64 = 832 blocks
  gemm_periods<<<g1, 256, 0, stream>>>(xf, W1, b1, pbuf);

  snn_scan<<<B_ROWS / 2, 320, 0, stream>>>(pbuf, W2, b2, outp);
}